// Round 2
// baseline (449.996 us; speedup 1.0000x reference)
//
#include <hip/hip_runtime.h>

// ---------------------------------------------------------------------------
// GCNnet: 3x GCNConv (40->40->80->128) + global max pool + MLP(128->512->2) + softmax
// N=100000 nodes, E=1600000 edges, G=512 graphs.
// Round 10: R9's line-padding was a null (deg_count still 80us) -> the cost is
// device-scope atomics executing at the memory-side coherence point (8 XCD L2s
// are not cross-coherent), ~20G atomics/s cap + ~32B HBM write per atomic.
// Fix: 8 histogram replicas, one per physical XCD (s_getreg HW_REG_XCC_ID),
// atomics issued with WORKGROUP scope -> global_atomic_add_x2 without device
// coherence flag -> executes in the XCD-local L2. rank packs (xcd, local_rank);
// scanA folds replicas + emits packed cross-replica prefix (8x8bit in u64).
// ---------------------------------------------------------------------------

static inline int cdiv(long a, int b) { return (int)((a + b - 1) / b); }
static inline size_t align256(size_t x) { return (x + 255) & ~(size_t)255; }

#define FXSCALE 16777216.0f           // 2^24
#define FXMASK  ((1ULL << 40) - 1)
#define SCHUNK  1024                  // elements per scan block
#define NXCD    8

__device__ __forceinline__ float bf2f(unsigned short u) {
    return __uint_as_float(((unsigned int)u) << 16);
}
__device__ __forceinline__ unsigned short f2bf(float f) {   // round-nearest-even
    unsigned int u = __float_as_uint(f);
    return (unsigned short)((u + 0x7FFFu + ((u >> 16) & 1u)) >> 16);
}
__device__ __forceinline__ int xcc_id() {
    int x;
    asm volatile("s_getreg_b32 %0, hwreg(HW_REG_XCC_ID)" : "=s"(x));
    return x & (NXCD - 1);
}

// one u64 atomic per edge into the XCD-local replica: high 24 bits count,
// low 40 bits fixed-point weight sum. Workgroup scope keeps the RMW in the
// local L2 (all workgroups with the same XCC_ID share that L2 -> coherent).
// rank[e] = (xcd << 26) | local_rank.
// Fused: x f32 -> bf16 bulk convert (independent work, rides along).
__global__ void deg_count_kernel(const int* __restrict__ col, const float* __restrict__ w,
                                 unsigned long long* __restrict__ packed,  // [NXCD][N]
                                 int* __restrict__ rank,
                                 const float* __restrict__ x, ushort* __restrict__ xbf,
                                 int E, int n4, int N) {
    int e = blockIdx.x * blockDim.x + threadIdx.x;
    int r = xcc_id();
    float4 v;
    if (e < n4) v = ((const float4*)x)[e];          // issue conversion load first
    if (e < E) {
        int c = col[e];
        unsigned long long fx = (unsigned long long)llrintf(w[e] * FXSCALE);
        unsigned long long old = __hip_atomic_fetch_add(
            packed + (size_t)r * N + c, (1ULL << 40) | fx,
            __ATOMIC_RELAXED, __HIP_MEMORY_SCOPE_WORKGROUP);
        rank[e] = (int)(((unsigned int)(old >> 40)) | ((unsigned int)r << 26));
    }
    if (e < n4)
        ((ushort4*)xbf)[e] = make_ushort4(f2bf(v.x), f2bf(v.y), f2bf(v.z), f2bf(v.w));
}

// scan phase A: fold NXCD replicas per node -> total count/weight, dinv,
// compact cnt, packed cross-replica exclusive prefix (8 bits per replica).
// Raw u64 sum is safe: per-replica weight-sum < 2^33 << 2^40 (no carry into
// the count field); counts add in the high bits.
__global__ void scanA_kernel(const unsigned long long* __restrict__ packed,
                             float* __restrict__ dinv, int* __restrict__ cnt,
                             unsigned long long* __restrict__ prefx,
                             int* __restrict__ blockSums, int N) {
    __shared__ int wred[4];
    int tid = threadIdx.x, lane = tid & 63, wid = tid >> 6;
    int i0 = blockIdx.x * SCHUNK + tid * 4;
    int s = 0;
#pragma unroll
    for (int k = 0; k < 4; ++k) {
        int i = i0 + k;
        if (i < N) {
            unsigned long long tot = 0, pp = 0;
            unsigned int run = 0;
#pragma unroll
            for (int r = 0; r < NXCD; ++r) {
                unsigned long long p = packed[(size_t)r * N + i];
                pp |= (unsigned long long)(run & 255u) << (8 * r);
                run += (unsigned int)(p >> 40);
                tot += p;
            }
            s += (int)run;
            cnt[i] = (int)run;
            prefx[i] = pp;
            float deg = (float)(tot & FXMASK) * (1.0f / FXSCALE);
            dinv[i] = rsqrtf(deg + 1.0f);
        }
    }
#pragma unroll
    for (int off = 32; off > 0; off >>= 1) s += __shfl_down(s, off, 64);
    if (lane == 0) wred[wid] = s;
    __syncthreads();
    if (tid == 0) blockSums[blockIdx.x] = wred[0] + wred[1] + wred[2] + wred[3];
}

// scan phase B: one block, exclusive scan of blockSums[nb] (nb <= 1024);
// writes total into offs[N].
__global__ void scanB_kernel(int* __restrict__ blockSums, int* __restrict__ offs,
                             int nb, int N) {
    __shared__ int wsum[16];
    int tid = threadIdx.x, lane = tid & 63, wid = tid >> 6;
    int v = (tid < nb) ? blockSums[tid] : 0;
    int incl = v;
#pragma unroll
    for (int off = 1; off < 64; off <<= 1) {
        int t = __shfl_up(incl, off, 64);
        if (lane >= off) incl += t;
    }
    if (lane == 63) wsum[wid] = incl;
    __syncthreads();
    if (wid == 0 && lane < 16) {
        int w = wsum[lane];
        int ic = w;
#pragma unroll
        for (int off = 1; off < 16; off <<= 1) {
            int t = __shfl_up(ic, off, 64);
            if (lane >= off) ic += t;
        }
        wsum[lane] = ic - w;   // exclusive
    }
    __syncthreads();
    if (tid < nb) blockSums[tid] = wsum[wid] + incl - v;   // exclusive prefix
    if (tid == 1023) offs[N] = wsum[15] + incl;            // grand total
}

// scan phase C: local exclusive scan (coalesced cnt reads) + block offset -> offs
__global__ void scanC_kernel(const int* __restrict__ cnt,
                             const int* __restrict__ blockSums,
                             int* __restrict__ offs, int N) {
    __shared__ int wsum[4];
    int tid = threadIdx.x, lane = tid & 63, wid = tid >> 6;
    int i0 = blockIdx.x * SCHUNK + tid * 4;
    int v0 = 0, v1 = 0, v2 = 0, v3 = 0;
    if (i0 + 0 < N) v0 = cnt[i0 + 0];
    if (i0 + 1 < N) v1 = cnt[i0 + 1];
    if (i0 + 2 < N) v2 = cnt[i0 + 2];
    if (i0 + 3 < N) v3 = cnt[i0 + 3];
    int sum = v0 + v1 + v2 + v3;
    int incl = sum;
#pragma unroll
    for (int off = 1; off < 64; off <<= 1) {
        int t = __shfl_up(incl, off, 64);
        if (lane >= off) incl += t;
    }
    if (lane == 63) wsum[wid] = incl;
    __syncthreads();
    if (tid == 0) {
        int c = 0;
#pragma unroll
        for (int k = 0; k < 4; ++k) { int t = wsum[k]; wsum[k] = c; c += t; }
    }
    __syncthreads();
    int pre = blockSums[blockIdx.x] + wsum[wid] + (incl - sum);
    if (i0 + 0 < N) offs[i0 + 0] = pre;
    if (i0 + 1 < N) offs[i0 + 1] = pre + v0;
    if (i0 + 2 < N) offs[i0 + 2] = pre + v0 + v1;
    if (i0 + 3 < N) offs[i0 + 3] = pre + v0 + v1 + v2;
}

// CSR fill, atomic-free: pos = offs[col] + crossReplicaPrefix + local rank;
// perm = {row, norm bits} (8B store)
__global__ void fill_kernel(const int* __restrict__ row, const int* __restrict__ col,
                            const float* __restrict__ w, const int* __restrict__ rank,
                            const float* __restrict__ dinv, const int* __restrict__ offs,
                            const unsigned long long* __restrict__ prefx,
                            int2* __restrict__ perm, int E) {
    int e = blockIdx.x * blockDim.x + threadIdx.x;
    if (e >= E) return;
    int r = row[e], c = col[e];
    unsigned int rk = (unsigned int)rank[e];
    int xcd = (int)(rk >> 26);
    int rloc = (int)(rk & 0x03FFFFFFu);
    int pos = offs[c] + (int)((prefx[c] >> (8 * xcd)) & 255u) + rloc;
    float nm = dinv[r] * w[e] * dinv[c];
    perm[pos] = make_int2(r, __float_as_int(nm));
}

// agg[d] = sum_{e: col=d} H[row_e]*norm_e + dinv[d]^2*H[d]   (H in bf16)
// thread = (node, 4 feats); 4-edge unroll -> 4 independent load chains
template<int F>
__global__ void gather_kernel(const int* __restrict__ offs, const int2* __restrict__ perm,
                              const ushort* __restrict__ H, const float* __restrict__ dinv,
                              float* __restrict__ agg, int N) {
    constexpr int TPN = F / 4;
    int idx = blockIdx.x * blockDim.x + threadIdx.x;
    int node = idx / TPN, q = idx % TPN;
    if (node >= N) return;
    int s = offs[node], e = offs[node + 1];
    float4 a0 = make_float4(0.f, 0.f, 0.f, 0.f);
    float4 a1 = make_float4(0.f, 0.f, 0.f, 0.f);
    int j = s;
    for (; j + 4 <= e; j += 4) {
        int2 p0 = perm[j + 0], p1 = perm[j + 1], p2 = perm[j + 2], p3 = perm[j + 3];
        float m0 = __int_as_float(p0.y), m1 = __int_as_float(p1.y);
        float m2 = __int_as_float(p2.y), m3 = __int_as_float(p3.y);
        ushort4 u0 = *(const ushort4*)(H + (long)p0.x * F + q * 4);
        ushort4 u1 = *(const ushort4*)(H + (long)p1.x * F + q * 4);
        ushort4 u2 = *(const ushort4*)(H + (long)p2.x * F + q * 4);
        ushort4 u3 = *(const ushort4*)(H + (long)p3.x * F + q * 4);
        a0.x += bf2f(u0.x) * m0; a0.y += bf2f(u0.y) * m0;
        a0.z += bf2f(u0.z) * m0; a0.w += bf2f(u0.w) * m0;
        a1.x += bf2f(u1.x) * m1; a1.y += bf2f(u1.y) * m1;
        a1.z += bf2f(u1.z) * m1; a1.w += bf2f(u1.w) * m1;
        a0.x += bf2f(u2.x) * m2; a0.y += bf2f(u2.y) * m2;
        a0.z += bf2f(u2.z) * m2; a0.w += bf2f(u2.w) * m2;
        a1.x += bf2f(u3.x) * m3; a1.y += bf2f(u3.y) * m3;
        a1.z += bf2f(u3.z) * m3; a1.w += bf2f(u3.w) * m3;
    }
    for (; j < e; ++j) {
        int2 p = perm[j];
        float nm = __int_as_float(p.y);
        ushort4 u = *(const ushort4*)(H + (long)p.x * F + q * 4);
        a0.x += bf2f(u.x) * nm; a0.y += bf2f(u.y) * nm;
        a0.z += bf2f(u.z) * nm; a0.w += bf2f(u.w) * nm;
    }
    float di = dinv[node], d2 = di * di;
    ushort4 su = *(const ushort4*)(H + (long)node * F + q * 4);
    float4 o = make_float4(a0.x + a1.x + d2 * bf2f(su.x), a0.y + a1.y + d2 * bf2f(su.y),
                           a0.z + a1.z + d2 * bf2f(su.z), a0.w + a1.w + d2 * bf2f(su.w));
    *(float4*)(agg + (long)node * F + q * 4) = o;
}

// out[N,FOUT] = relu(X[N,K] @ W[K,FOUT] + bias)
// thread = (NPT=4 consecutive nodes, 4 feats), q-minor lanes (coalesced X/W/out);
// W staged in LDS; per W ds_read_b128: 16 FMAs. Block owns NPB consecutive nodes.
// BF16OUT: store ushort4 bf16. FUSE_POOL: hierarchical max-pool (2-graph LDS
// window, zero-skipping flush; direct global atomics if rel >= 2).
template<int K, int FOUT, int BLK, bool FUSE_POOL, bool BF16OUT>
__global__ __launch_bounds__(BLK)
void gemm_kernel(const float* __restrict__ X, const float* __restrict__ W,
                 const float* __restrict__ bias, void* __restrict__ out,
                 const int* __restrict__ batch, unsigned int* __restrict__ g, int N) {
    constexpr int NPT = 4;                 // nodes per thread
    constexpr int TPQ = FOUT / 4;          // feature-group slots
    constexpr int PSLOTS = BLK / TPQ;      // node-groups per block
    constexpr int NPB = PSLOTS * NPT;      // nodes per block
    __shared__ float wsm[K * FOUT];
    __shared__ unsigned int gma[FUSE_POOL ? 2 * FOUT : 1];
    __shared__ int gfirst;
    for (int i = threadIdx.x; i < K * FOUT; i += BLK) wsm[i] = W[i];
    if (FUSE_POOL) {
        if (threadIdx.x == 0) gfirst = batch[min((int)(blockIdx.x * NPB), N - 1)];
        for (int i = threadIdx.x; i < 2 * FOUT; i += BLK) gma[i] = 0u;
    }
    __syncthreads();

    int q = threadIdx.x % TPQ, p = threadIdx.x / TPQ;
    long nbase = (long)blockIdx.x * NPB + (long)p * NPT;

    float4 acc[NPT];
#pragma unroll
    for (int t = 0; t < NPT; ++t) acc[t] = make_float4(0.f, 0.f, 0.f, 0.f);

    const float* wq = wsm + q * 4;
#pragma unroll 4
    for (int i = 0; i < K / 4; ++i) {
        float4 xv[NPT];
#pragma unroll
        for (int t = 0; t < NPT; ++t) {
            long n = nbase + t; if (n >= N) n = N - 1;    // clamp (masked at store)
            xv[t] = *(const float4*)(X + n * K + i * 4);
        }
#pragma unroll
        for (int j = 0; j < 4; ++j) {
            float4 wv = *(const float4*)(wq + (i * 4 + j) * FOUT);
#pragma unroll
            for (int t = 0; t < NPT; ++t) {
                float v = ((const float*)&xv[t])[j];
                acc[t].x += v * wv.x; acc[t].y += v * wv.y;
                acc[t].z += v * wv.z; acc[t].w += v * wv.w;
            }
        }
    }

    float4 bv = *(const float4*)(bias + q * 4);
#pragma unroll
    for (int t = 0; t < NPT; ++t) {
        acc[t].x = fmaxf(acc[t].x + bv.x, 0.f);
        acc[t].y = fmaxf(acc[t].y + bv.y, 0.f);
        acc[t].z = fmaxf(acc[t].z + bv.z, 0.f);
        acc[t].w = fmaxf(acc[t].w + bv.w, 0.f);
    }

    if (!FUSE_POOL) {
        if (BF16OUT) {
            ushort* ob = (ushort*)out;
#pragma unroll
            for (int t = 0; t < NPT; ++t) {
                long n = nbase + t;
                if (n < N)
                    *(ushort4*)(ob + n * FOUT + q * 4) =
                        make_ushort4(f2bf(acc[t].x), f2bf(acc[t].y),
                                     f2bf(acc[t].z), f2bf(acc[t].w));
            }
        } else {
            float* of = (float*)out;
#pragma unroll
            for (int t = 0; t < NPT; ++t) {
                long n = nbase + t;
                if (n < N) *(float4*)(of + n * FOUT + q * 4) = acc[t];
            }
        }
        return;
    }

    // ---- hierarchical pool ----
#pragma unroll
    for (int t = 0; t < NPT; ++t) {
        long n = nbase + t;
        if (n < N) {
            unsigned int bx = __float_as_uint(acc[t].x), by = __float_as_uint(acc[t].y);
            unsigned int bz = __float_as_uint(acc[t].z), bw = __float_as_uint(acc[t].w);
            int rel = batch[n] - gfirst;
            if (rel < 2) {
                unsigned int* d = gma + rel * FOUT + q * 4;
                atomicMax(d + 0, bx); atomicMax(d + 1, by);
                atomicMax(d + 2, bz); atomicMax(d + 3, bw);
            } else {
                unsigned int* d = g + (long)batch[n] * FOUT + q * 4;
                atomicMax(d + 0, bx); atomicMax(d + 1, by);
                atomicMax(d + 2, bz); atomicMax(d + 3, bw);
            }
        }
    }
    __syncthreads();
    for (int i = threadIdx.x; i < 2 * FOUT; i += BLK) {
        unsigned int v = gma[i];
        if (v) atomicMax(&g[(long)(gfirst + i / FOUT) * FOUT + (i % FOUT)], v);
    }
}

// one block per graph: relu(g@Wfc1+bfc1) @ Wfc2 + bfc2 -> softmax
__global__ void fc_kernel(const float* __restrict__ g, const float* __restrict__ Wfc1,
                          const float* __restrict__ bfc1, const float* __restrict__ Wfc2,
                          const float* __restrict__ bfc2, float* __restrict__ out) {
    __shared__ float gs[128];
    __shared__ float red0[256], red1[256];
    int b = blockIdx.x, tid = threadIdx.x;
    if (tid < 128) gs[tid] = g[b * 128 + tid];
    __syncthreads();
    float h0 = bfc1[tid], h1 = bfc1[tid + 256];
    for (int k = 0; k < 128; ++k) {
        float gv = gs[k];
        h0 += gv * Wfc1[k * 512 + tid];
        h1 += gv * Wfc1[k * 512 + tid + 256];
    }
    h0 = fmaxf(h0, 0.f); h1 = fmaxf(h1, 0.f);
    red0[tid] = h0 * Wfc2[tid * 2 + 0] + h1 * Wfc2[(tid + 256) * 2 + 0];
    red1[tid] = h0 * Wfc2[tid * 2 + 1] + h1 * Wfc2[(tid + 256) * 2 + 1];
    __syncthreads();
    for (int s = 128; s > 0; s >>= 1) {
        if (tid < s) { red0[tid] += red0[tid + s]; red1[tid] += red1[tid + s]; }
        __syncthreads();
    }
    if (tid == 0) {
        float L0 = red0[0] + bfc2[0], L1 = red1[0] + bfc2[1];
        float m = fmaxf(L0, L1);
        float e0 = expf(L0 - m), e1 = expf(L1 - m);
        float inv = 1.f / (e0 + e1);
        out[b * 2 + 0] = e0 * inv;
        out[b * 2 + 1] = e1 * inv;
    }
}

extern "C" void kernel_launch(void* const* d_in, const int* in_sizes, int n_in,
                              void* d_out, int out_size, void* d_ws, size_t ws_size,
                              hipStream_t stream) {
    const float* x     = (const float*)d_in[0];
    const int*   ei    = (const int*)d_in[1];
    const float* ew    = (const float*)d_in[2];
    const int*   batch = (const int*)d_in[3];
    const float* W1    = (const float*)d_in[4];
    const float* b1    = (const float*)d_in[5];
    const float* W2    = (const float*)d_in[6];
    const float* b2    = (const float*)d_in[7];
    const float* W3    = (const float*)d_in[8];
    const float* b3    = (const float*)d_in[9];
    const float* Wfc1  = (const float*)d_in[10];
    const float* bfc1  = (const float*)d_in[11];
    const float* Wfc2  = (const float*)d_in[12];
    const float* bfc2  = (const float*)d_in[13];

    const int N = in_sizes[3];      // 100000
    const int E = in_sizes[2];      // 1600000
    const int* row = ei;
    const int* col = ei + E;

    char* ws = (char*)d_ws;
    float* dinv   = (float*)ws;              ws += align256((size_t)N * 4);
    int*   offs   = (int*)ws;                ws += align256((size_t)(N + 1) * 4);
    int*   bsums  = (int*)ws;                ws += align256((size_t)1024 * 4);
    int2*  perm   = (int2*)ws;               ws += align256((size_t)E * 8);
    float* bufA   = (float*)ws;              ws += align256((size_t)N * 128 * 4);  // agg f32
    ushort* bufH  = (ushort*)ws;             ws += align256((size_t)N * 128 * 2);  // H bf16
    ushort* xbf   = (ushort*)ws;             ws += align256((size_t)N * 40 * 2);   // x bf16
    float* g      = (float*)ws;              ws += align256((size_t)512 * 128 * 4);

    // transient buffers aliased into bufA (all dead before gather1 writes bufA):
    // rank[E] (6.4MB) | packed[NXCD][N] u64 (6.4MB) | prefx[N] u64 (0.8MB) | cnt[N] (0.4MB)
    int* rank = (int*)bufA;
    unsigned long long* packed =
        (unsigned long long*)((char*)bufA + align256((size_t)E * 4));
    unsigned long long* prefx =
        (unsigned long long*)((char*)packed + align256((size_t)NXCD * N * 8));
    int* cnt = (int*)((char*)prefx + align256((size_t)N * 8));

    const int B = 256;
    const int nScanBlocks = cdiv(N, SCHUNK);   // 98 for N=100000 (<= 1024)
    const int n4 = N * 10;                     // x float4 count (N*40 floats)

    // --- gcn_norm + CSR build (f2bf fused into deg_count) ---
    hipMemsetAsync(packed, 0, (size_t)NXCD * N * 8, stream);
    deg_count_kernel<<<cdiv(E > n4 ? E : n4, B), B, 0, stream>>>(
        col, ew, packed, rank, x, xbf, E, n4, N);
    scanA_kernel<<<nScanBlocks, B, 0, stream>>>(packed, dinv, cnt, prefx, bsums, N);
    scanB_kernel<<<1, 1024, 0, stream>>>(bsums, offs, nScanBlocks, N);
    scanC_kernel<<<nScanBlocks, B, 0, stream>>>(cnt, bsums, offs, N);
    fill_kernel<<<cdiv(E, B), B, 0, stream>>>(row, col, ew, rank, dinv, offs, prefx,
                                              perm, E);

    // --- conv1: agg = A*x (40-wide bf16), H1 = relu(agg@W1 + b1) -> bufH (bf16) ---
    gather_kernel<40><<<cdiv((long)N * 10, B), B, 0, stream>>>(
        offs, perm, xbf, dinv, bufA, N);
    gemm_kernel<40, 40, 320, false, true><<<cdiv(N, 128), 320, 0, stream>>>(
        bufA, W1, b1, bufH, nullptr, nullptr, N);

    // --- conv2: agg = A*H1 (40-wide bf16), H2 = relu(agg@W2 + b2) -> bufH (bf16) ---
    gather_kernel<40><<<cdiv((long)N * 10, B), B, 0, stream>>>(
        offs, perm, bufH, dinv, bufA, N);
    gemm_kernel<40, 80, 320, false, true><<<cdiv(N, 64), 320, 0, stream>>>(
        bufA, W2, b2, bufH, nullptr, nullptr, N);

    // --- conv3: agg = A*H2 (80-wide bf16), pool(relu(agg@W3 + b3)) -> g ---
    gather_kernel<80><<<cdiv((long)N * 20, B), B, 0, stream>>>(
        offs, perm, bufH, dinv, bufA, N);
    hipMemsetAsync(g, 0, (size_t)512 * 128 * 4, stream);
    gemm_kernel<80, 128, 256, true, false><<<cdiv(N, 32), 256, 0, stream>>>(
        bufA, W3, b3, nullptr, batch, (unsigned int*)g, N);

    // --- MLP + softmax ---
    fc_kernel<<<512, 256, 0, stream>>>(g, Wfc1, bfc1, Wfc2, bfc2, (float*)d_out);
}

// Round 3
// 397.016 us; speedup vs baseline: 1.1334x; 1.1334x over previous
//
#include <hip/hip_runtime.h>

// ---------------------------------------------------------------------------
// GCNnet: 3x GCNConv (40->40->80->128) + global max pool + MLP(128->512->2) + softmax
// N=100000 nodes, E=1600000 edges, G=512 graphs.
// Round 11: R9 (line padding) and R10 (XCD replicas + workgroup scope) were
// both nulls with identical counters -> global returning atomics on gfx950
// cost a fixed ~15cy/channel at the TCC atomic units with ~40B/op HBM
// write-through, independent of address layout or scope. 1.6M ops / ~128
// channels = ~78us floor. Fix: eliminate per-edge global atomics entirely.
// Atomic-free CSR build = 2-level counting sort (bucket = col>>6, 64 nodes):
//   histA (LDS histograms, f2bf fused) -> scan over (bucket,tile) cells ->
//   scatterC (LDS cursors -> semi[] bucket-grouped) ->
//   fineD (per-bucket LDS fine sort -> perm/offs/dinv) ->
//   normE (perm.w = dinv[r]*w*dinv[c]).
// All atomics are LDS-local. Downstream (gather/gemm/fc) unchanged.
// ---------------------------------------------------------------------------

static inline int cdiv(long a, int b) { return (int)((a + b - 1) / b); }
static inline size_t align256(size_t x) { return (x + 255) & ~(size_t)255; }

#define FXSCALE 16777216.0f           // 2^24
#define SCHUNK  1024                  // elements per scan block
#define BKT_SHIFT 6                   // 64 nodes per bucket
#define MAXNB   2048                  // LDS histogram capacity (N <= 131072)
#define TB      256                   // histogram tiles

__device__ __forceinline__ float bf2f(unsigned short u) {
    return __uint_as_float(((unsigned int)u) << 16);
}
__device__ __forceinline__ unsigned short f2bf(float f) {   // round-nearest-even
    unsigned int u = __float_as_uint(f);
    return (unsigned short)((u + 0x7FFFu + ((u >> 16) & 1u)) >> 16);
}

// Pass A: per-tile LDS histogram over NB buckets (bucket = col>>6).
// gHist[tile][bucket]. Fused: x f32 -> bf16 bulk convert.
__global__ __launch_bounds__(512)
void histA_kernel(const int* __restrict__ col, unsigned int* __restrict__ gHist,
                  int E, int NB, int chunk,
                  const float* __restrict__ x, ushort* __restrict__ xbf, long n4) {
    __shared__ unsigned int hist[MAXNB];
    int t = blockIdx.x;
    for (int i = threadIdx.x; i < NB; i += 512) hist[i] = 0u;
    __syncthreads();
    int s = t * chunk, e = min(s + chunk, E);
    for (int i = s + threadIdx.x; i < e; i += 512)
        atomicAdd(&hist[(unsigned int)col[i] >> BKT_SHIFT], 1u);
    // fused f2bf (independent work)
    long gid = (long)t * 512 + threadIdx.x, gstride = (long)TB * 512;
    for (long i = gid; i < n4; i += gstride) {
        float4 v = ((const float4*)x)[i];
        ((ushort4*)xbf)[i] = make_ushort4(f2bf(v.x), f2bf(v.y), f2bf(v.z), f2bf(v.w));
    }
    __syncthreads();
    for (int b = threadIdx.x; b < NB; b += 512)
        gHist[(size_t)t * NB + b] = hist[b];
}

// scan phase A (histogram variant): per-block sums of the bucket-major view
// element i -> gHist[(i&255)*NB + (i>>8)]   (i = bucket*256 + tile)
__global__ void scanAH_kernel(const unsigned int* __restrict__ gHist,
                              int* __restrict__ blockSums, int TOT, int NB) {
    __shared__ int wred[4];
    int tid = threadIdx.x, lane = tid & 63, wid = tid >> 6;
    int i0 = blockIdx.x * SCHUNK + tid * 4;
    int s = 0;
#pragma unroll
    for (int k = 0; k < 4; ++k) {
        int i = i0 + k;
        if (i < TOT) s += (int)gHist[(size_t)(i & 255) * NB + (i >> 8)];
    }
#pragma unroll
    for (int off = 32; off > 0; off >>= 1) s += __shfl_down(s, off, 64);
    if (lane == 0) wred[wid] = s;
    __syncthreads();
    if (tid == 0) blockSums[blockIdx.x] = wred[0] + wred[1] + wred[2] + wred[3];
}

// scan phase B: one block, exclusive scan of blockSums[nb] (nb <= 1024);
// writes grand total into offs[N] (= E, harmless/correct).
__global__ void scanB_kernel(int* __restrict__ blockSums, int* __restrict__ offs,
                             int nb, int N) {
    __shared__ int wsum[16];
    int tid = threadIdx.x, lane = tid & 63, wid = tid >> 6;
    int v = (tid < nb) ? blockSums[tid] : 0;
    int incl = v;
#pragma unroll
    for (int off = 1; off < 64; off <<= 1) {
        int t = __shfl_up(incl, off, 64);
        if (lane >= off) incl += t;
    }
    if (lane == 63) wsum[wid] = incl;
    __syncthreads();
    if (wid == 0 && lane < 16) {
        int w = wsum[lane];
        int ic = w;
#pragma unroll
        for (int off = 1; off < 16; off <<= 1) {
            int t = __shfl_up(ic, off, 64);
            if (lane >= off) ic += t;
        }
        wsum[lane] = ic - w;   // exclusive
    }
    __syncthreads();
    if (tid < nb) blockSums[tid] = wsum[wid] + incl - v;   // exclusive prefix
    if (tid == 1023) offs[N] = wsum[15] + incl;            // grand total
}

// scan phase C (histogram variant): local exclusive scan + block offset ->
// scanned[i] = global output cursor for (bucket = i>>8, tile = i&255)
__global__ void scanCH_kernel(const unsigned int* __restrict__ gHist,
                              const int* __restrict__ blockSums,
                              unsigned int* __restrict__ scanned, int TOT, int NB) {
    __shared__ int wsum[4];
    int tid = threadIdx.x, lane = tid & 63, wid = tid >> 6;
    int i0 = blockIdx.x * SCHUNK + tid * 4;
    int v0 = 0, v1 = 0, v2 = 0, v3 = 0;
    if (i0 + 0 < TOT) v0 = (int)gHist[(size_t)((i0 + 0) & 255) * NB + ((i0 + 0) >> 8)];
    if (i0 + 1 < TOT) v1 = (int)gHist[(size_t)((i0 + 1) & 255) * NB + ((i0 + 1) >> 8)];
    if (i0 + 2 < TOT) v2 = (int)gHist[(size_t)((i0 + 2) & 255) * NB + ((i0 + 2) >> 8)];
    if (i0 + 3 < TOT) v3 = (int)gHist[(size_t)((i0 + 3) & 255) * NB + ((i0 + 3) >> 8)];
    int sum = v0 + v1 + v2 + v3;
    int incl = sum;
#pragma unroll
    for (int off = 1; off < 64; off <<= 1) {
        int t = __shfl_up(incl, off, 64);
        if (lane >= off) incl += t;
    }
    if (lane == 63) wsum[wid] = incl;
    __syncthreads();
    if (tid == 0) {
        int c = 0;
#pragma unroll
        for (int k = 0; k < 4; ++k) { int t = wsum[k]; wsum[k] = c; c += t; }
    }
    __syncthreads();
    int pre = blockSums[blockIdx.x] + wsum[wid] + (incl - sum);
    if (i0 + 0 < TOT) scanned[i0 + 0] = (unsigned int)pre;
    if (i0 + 1 < TOT) scanned[i0 + 1] = (unsigned int)(pre + v0);
    if (i0 + 2 < TOT) scanned[i0 + 2] = (unsigned int)(pre + v0 + v1);
    if (i0 + 3 < TOT) scanned[i0 + 3] = (unsigned int)(pre + v0 + v1 + v2);
}

// Pass C: scatter edges into bucket-grouped semi[] via LDS cursors.
// semi[pos] = {row, col, wbits, 0}. Runs per (tile,bucket) are contiguous.
__global__ __launch_bounds__(512)
void scatterC_kernel(const int* __restrict__ row, const int* __restrict__ col,
                     const float* __restrict__ w,
                     const unsigned int* __restrict__ scanned,
                     int4* __restrict__ semi, int E, int NB, int chunk) {
    __shared__ unsigned int cur[MAXNB];
    int t = blockIdx.x;
    for (int b = threadIdx.x; b < NB; b += 512)
        cur[b] = scanned[(size_t)b * TB + t];
    __syncthreads();
    int s = t * chunk, e = min(s + chunk, E);
    for (int i = s + threadIdx.x; i < e; i += 512) {
        int c = col[i];
        unsigned int pos = atomicAdd(&cur[(unsigned int)c >> BKT_SHIFT], 1u);
        semi[pos] = make_int4(row[i], c, __float_as_int(w[i]), 0);
    }
}

// Pass D: one block per bucket (64 nodes). Fine counting sort by col&63,
// per-node weighted degree (fixed-point LDS atomics) -> perm {row,wbits},
// offs, dinv. All atomics LDS.
__global__ __launch_bounds__(256)
void fineD_kernel(const int4* __restrict__ semi, const unsigned int* __restrict__ scanned,
                  int* __restrict__ offs, float* __restrict__ dinv,
                  int2* __restrict__ perm, int E, int N, int NB) {
    __shared__ unsigned int cnt[64], cur[64], wsum[64];
    __shared__ int nodeOffs[64];
    int b = blockIdx.x, tid = threadIdx.x;
    int s = (int)scanned[(size_t)b * TB];
    int e = (b + 1 < NB) ? (int)scanned[(size_t)(b + 1) * TB] : E;
    if (tid < 64) { cnt[tid] = 0u; wsum[tid] = 0u; }
    __syncthreads();
    for (int i = s + tid; i < e; i += 256) {
        int4 v = semi[i];
        int c6 = v.y & 63;
        atomicAdd(&cnt[c6], 1u);
        atomicAdd(&wsum[c6], (unsigned int)llrintf(__int_as_float(v.z) * FXSCALE));
    }
    __syncthreads();
    if (tid < 64) {
        int v = (int)cnt[tid];
        int incl = v;
#pragma unroll
        for (int off = 1; off < 64; off <<= 1) {
            int u = __shfl_up(incl, off, 64);
            if (tid >= off) incl += u;
        }
        nodeOffs[tid] = incl - v;          // exclusive within bucket
        cur[tid] = (unsigned int)(incl - v);
    }
    __syncthreads();
    for (int i = s + tid; i < e; i += 256) {
        int4 v = semi[i];
        int c6 = v.y & 63;
        unsigned int r = atomicAdd(&cur[c6], 1u);
        perm[s + (int)r] = make_int2(v.x, v.z);   // {row, wbits}; norm in passE
    }
    if (tid < 64) {
        int node = (b << BKT_SHIFT) + tid;
        if (node < N) {
            offs[node] = s + nodeOffs[tid];
            float deg = (float)wsum[tid] * (1.0f / FXSCALE);
            dinv[node] = rsqrtf(deg + 1.0f);
        }
    }
    if (b == NB - 1 && tid == 0) offs[N] = E;
}

// Pass E: perm.y = dinv[row] * w * dinv[col]  (thread per destination node)
__global__ void normE_kernel(const int* __restrict__ offs, const float* __restrict__ dinv,
                             int2* __restrict__ perm, int N) {
    int n = blockIdx.x * blockDim.x + threadIdx.x;
    if (n >= N) return;
    int s = offs[n], e = offs[n + 1];
    float dc = dinv[n];
    for (int j = s; j < e; ++j) {
        int2 p = perm[j];
        float nm = dinv[p.x] * __int_as_float(p.y) * dc;
        perm[j] = make_int2(p.x, __float_as_int(nm));
    }
}

// agg[d] = sum_{e: col=d} H[row_e]*norm_e + dinv[d]^2*H[d]   (H in bf16)
// thread = (node, 4 feats); 4-edge unroll -> 4 independent load chains
template<int F>
__global__ void gather_kernel(const int* __restrict__ offs, const int2* __restrict__ perm,
                              const ushort* __restrict__ H, const float* __restrict__ dinv,
                              float* __restrict__ agg, int N) {
    constexpr int TPN = F / 4;
    int idx = blockIdx.x * blockDim.x + threadIdx.x;
    int node = idx / TPN, q = idx % TPN;
    if (node >= N) return;
    int s = offs[node], e = offs[node + 1];
    float4 a0 = make_float4(0.f, 0.f, 0.f, 0.f);
    float4 a1 = make_float4(0.f, 0.f, 0.f, 0.f);
    int j = s;
    for (; j + 4 <= e; j += 4) {
        int2 p0 = perm[j + 0], p1 = perm[j + 1], p2 = perm[j + 2], p3 = perm[j + 3];
        float m0 = __int_as_float(p0.y), m1 = __int_as_float(p1.y);
        float m2 = __int_as_float(p2.y), m3 = __int_as_float(p3.y);
        ushort4 u0 = *(const ushort4*)(H + (long)p0.x * F + q * 4);
        ushort4 u1 = *(const ushort4*)(H + (long)p1.x * F + q * 4);
        ushort4 u2 = *(const ushort4*)(H + (long)p2.x * F + q * 4);
        ushort4 u3 = *(const ushort4*)(H + (long)p3.x * F + q * 4);
        a0.x += bf2f(u0.x) * m0; a0.y += bf2f(u0.y) * m0;
        a0.z += bf2f(u0.z) * m0; a0.w += bf2f(u0.w) * m0;
        a1.x += bf2f(u1.x) * m1; a1.y += bf2f(u1.y) * m1;
        a1.z += bf2f(u1.z) * m1; a1.w += bf2f(u1.w) * m1;
        a0.x += bf2f(u2.x) * m2; a0.y += bf2f(u2.y) * m2;
        a0.z += bf2f(u2.z) * m2; a0.w += bf2f(u2.w) * m2;
        a1.x += bf2f(u3.x) * m3; a1.y += bf2f(u3.y) * m3;
        a1.z += bf2f(u3.z) * m3; a1.w += bf2f(u3.w) * m3;
    }
    for (; j < e; ++j) {
        int2 p = perm[j];
        float nm = __int_as_float(p.y);
        ushort4 u = *(const ushort4*)(H + (long)p.x * F + q * 4);
        a0.x += bf2f(u.x) * nm; a0.y += bf2f(u.y) * nm;
        a0.z += bf2f(u.z) * nm; a0.w += bf2f(u.w) * nm;
    }
    float di = dinv[node], d2 = di * di;
    ushort4 su = *(const ushort4*)(H + (long)node * F + q * 4);
    float4 o = make_float4(a0.x + a1.x + d2 * bf2f(su.x), a0.y + a1.y + d2 * bf2f(su.y),
                           a0.z + a1.z + d2 * bf2f(su.z), a0.w + a1.w + d2 * bf2f(su.w));
    *(float4*)(agg + (long)node * F + q * 4) = o;
}

// out[N,FOUT] = relu(X[N,K] @ W[K,FOUT] + bias)
// thread = (NPT=4 consecutive nodes, 4 feats), q-minor lanes (coalesced X/W/out);
// W staged in LDS; per W ds_read_b128: 16 FMAs. Block owns NPB consecutive nodes.
// BF16OUT: store ushort4 bf16. FUSE_POOL: hierarchical max-pool (2-graph LDS
// window, zero-skipping flush; direct global atomics if rel >= 2).
template<int K, int FOUT, int BLK, bool FUSE_POOL, bool BF16OUT>
__global__ __launch_bounds__(BLK)
void gemm_kernel(const float* __restrict__ X, const float* __restrict__ W,
                 const float* __restrict__ bias, void* __restrict__ out,
                 const int* __restrict__ batch, unsigned int* __restrict__ g, int N) {
    constexpr int NPT = 4;                 // nodes per thread
    constexpr int TPQ = FOUT / 4;          // feature-group slots
    constexpr int PSLOTS = BLK / TPQ;      // node-groups per block
    constexpr int NPB = PSLOTS * NPT;      // nodes per block
    __shared__ float wsm[K * FOUT];
    __shared__ unsigned int gma[FUSE_POOL ? 2 * FOUT : 1];
    __shared__ int gfirst;
    for (int i = threadIdx.x; i < K * FOUT; i += BLK) wsm[i] = W[i];
    if (FUSE_POOL) {
        if (threadIdx.x == 0) gfirst = batch[min((int)(blockIdx.x * NPB), N - 1)];
        for (int i = threadIdx.x; i < 2 * FOUT; i += BLK) gma[i] = 0u;
    }
    __syncthreads();

    int q = threadIdx.x % TPQ, p = threadIdx.x / TPQ;
    long nbase = (long)blockIdx.x * NPB + (long)p * NPT;

    float4 acc[NPT];
#pragma unroll
    for (int t = 0; t < NPT; ++t) acc[t] = make_float4(0.f, 0.f, 0.f, 0.f);

    const float* wq = wsm + q * 4;
#pragma unroll 4
    for (int i = 0; i < K / 4; ++i) {
        float4 xv[NPT];
#pragma unroll
        for (int t = 0; t < NPT; ++t) {
            long n = nbase + t; if (n >= N) n = N - 1;    // clamp (masked at store)
            xv[t] = *(const float4*)(X + n * K + i * 4);
        }
#pragma unroll
        for (int j = 0; j < 4; ++j) {
            float4 wv = *(const float4*)(wq + (i * 4 + j) * FOUT);
#pragma unroll
            for (int t = 0; t < NPT; ++t) {
                float v = ((const float*)&xv[t])[j];
                acc[t].x += v * wv.x; acc[t].y += v * wv.y;
                acc[t].z += v * wv.z; acc[t].w += v * wv.w;
            }
        }
    }

    float4 bv = *(const float4*)(bias + q * 4);
#pragma unroll
    for (int t = 0; t < NPT; ++t) {
        acc[t].x = fmaxf(acc[t].x + bv.x, 0.f);
        acc[t].y = fmaxf(acc[t].y + bv.y, 0.f);
        acc[t].z = fmaxf(acc[t].z + bv.z, 0.f);
        acc[t].w = fmaxf(acc[t].w + bv.w, 0.f);
    }

    if (!FUSE_POOL) {
        if (BF16OUT) {
            ushort* ob = (ushort*)out;
#pragma unroll
            for (int t = 0; t < NPT; ++t) {
                long n = nbase + t;
                if (n < N)
                    *(ushort4*)(ob + n * FOUT + q * 4) =
                        make_ushort4(f2bf(acc[t].x), f2bf(acc[t].y),
                                     f2bf(acc[t].z), f2bf(acc[t].w));
            }
        } else {
            float* of = (float*)out;
#pragma unroll
            for (int t = 0; t < NPT; ++t) {
                long n = nbase + t;
                if (n < N) *(float4*)(of + n * FOUT + q * 4) = acc[t];
            }
        }
        return;
    }

    // ---- hierarchical pool ----
#pragma unroll
    for (int t = 0; t < NPT; ++t) {
        long n = nbase + t;
        if (n < N) {
            unsigned int bx = __float_as_uint(acc[t].x), by = __float_as_uint(acc[t].y);
            unsigned int bz = __float_as_uint(acc[t].z), bw = __float_as_uint(acc[t].w);
            int rel = batch[n] - gfirst;
            if (rel < 2) {
                unsigned int* d = gma + rel * FOUT + q * 4;
                atomicMax(d + 0, bx); atomicMax(d + 1, by);
                atomicMax(d + 2, bz); atomicMax(d + 3, bw);
            } else {
                unsigned int* d = g + (long)batch[n] * FOUT + q * 4;
                atomicMax(d + 0, bx); atomicMax(d + 1, by);
                atomicMax(d + 2, bz); atomicMax(d + 3, bw);
            }
        }
    }
    __syncthreads();
    for (int i = threadIdx.x; i < 2 * FOUT; i += BLK) {
        unsigned int v = gma[i];
        if (v) atomicMax(&g[(long)(gfirst + i / FOUT) * FOUT + (i % FOUT)], v);
    }
}

// one block per graph: relu(g@Wfc1+bfc1) @ Wfc2 + bfc2 -> softmax
__global__ void fc_kernel(const float* __restrict__ g, const float* __restrict__ Wfc1,
                          const float* __restrict__ bfc1, const float* __restrict__ Wfc2,
                          const float* __restrict__ bfc2, float* __restrict__ out) {
    __shared__ float gs[128];
    __shared__ float red0[256], red1[256];
    int b = blockIdx.x, tid = threadIdx.x;
    if (tid < 128) gs[tid] = g[b * 128 + tid];
    __syncthreads();
    float h0 = bfc1[tid], h1 = bfc1[tid + 256];
    for (int k = 0; k < 128; ++k) {
        float gv = gs[k];
        h0 += gv * Wfc1[k * 512 + tid];
        h1 += gv * Wfc1[k * 512 + tid + 256];
    }
    h0 = fmaxf(h0, 0.f); h1 = fmaxf(h1, 0.f);
    red0[tid] = h0 * Wfc2[tid * 2 + 0] + h1 * Wfc2[(tid + 256) * 2 + 0];
    red1[tid] = h0 * Wfc2[tid * 2 + 1] + h1 * Wfc2[(tid + 256) * 2 + 1];
    __syncthreads();
    for (int s = 128; s > 0; s >>= 1) {
        if (tid < s) { red0[tid] += red0[tid + s]; red1[tid] += red1[tid + s]; }
        __syncthreads();
    }
    if (tid == 0) {
        float L0 = red0[0] + bfc2[0], L1 = red1[0] + bfc2[1];
        float m = fmaxf(L0, L1);
        float e0 = expf(L0 - m), e1 = expf(L1 - m);
        float inv = 1.f / (e0 + e1);
        out[b * 2 + 0] = e0 * inv;
        out[b * 2 + 1] = e1 * inv;
    }
}

extern "C" void kernel_launch(void* const* d_in, const int* in_sizes, int n_in,
                              void* d_out, int out_size, void* d_ws, size_t ws_size,
                              hipStream_t stream) {
    const float* x     = (const float*)d_in[0];
    const int*   ei    = (const int*)d_in[1];
    const float* ew    = (const float*)d_in[2];
    const int*   batch = (const int*)d_in[3];
    const float* W1    = (const float*)d_in[4];
    const float* b1    = (const float*)d_in[5];
    const float* W2    = (const float*)d_in[6];
    const float* b2    = (const float*)d_in[7];
    const float* W3    = (const float*)d_in[8];
    const float* b3    = (const float*)d_in[9];
    const float* Wfc1  = (const float*)d_in[10];
    const float* bfc1  = (const float*)d_in[11];
    const float* Wfc2  = (const float*)d_in[12];
    const float* bfc2  = (const float*)d_in[13];

    const int N = in_sizes[3];      // 100000
    const int E = in_sizes[2];      // 1600000
    const int* row = ei;
    const int* col = ei + E;

    char* ws = (char*)d_ws;
    float* dinv   = (float*)ws;              ws += align256((size_t)N * 4);
    int*   offs   = (int*)ws;                ws += align256((size_t)(N + 1) * 4);
    int*   bsums  = (int*)ws;                ws += align256((size_t)1024 * 4);
    int2*  perm   = (int2*)ws;               ws += align256((size_t)E * 8);
    float* bufA   = (float*)ws;              ws += align256((size_t)N * 128 * 4);  // agg f32
    ushort* bufH  = (ushort*)ws;             ws += align256((size_t)N * 128 * 2);  // H bf16
    ushort* xbf   = (ushort*)ws;             ws += align256((size_t)N * 40 * 2);   // x bf16
    float* g      = (float*)ws;              ws += align256((size_t)512 * 128 * 4);

    const int NB   = cdiv(N, 64);            // 1563 buckets (<= MAXNB)
    const int TOT  = NB * TB;                // (bucket, tile) cells = 400128
    const int chunkE = cdiv(E, TB);          // edges per tile = 6250
    const int nScanH = cdiv(TOT, SCHUNK);    // 391 (<= 1024)

    // transients aliased into bufA (51.2MB; all dead before gather1 writes bufA):
    // semi int4 (25.6MB) | gHist u32[TOT] (1.6MB) | scanned u32[TOT] (1.6MB)
    int4* semi = (int4*)bufA;
    unsigned int* gHist =
        (unsigned int*)((char*)bufA + align256((size_t)E * 16));
    unsigned int* scanned =
        (unsigned int*)((char*)gHist + align256((size_t)TOT * 4));

    const int B = 256;

    // --- atomic-free CSR build ---
    histA_kernel<<<TB, 512, 0, stream>>>(col, gHist, E, NB, chunkE,
                                         x, xbf, (long)N * 10);
    scanAH_kernel<<<nScanH, B, 0, stream>>>(gHist, bsums, TOT, NB);
    scanB_kernel<<<1, 1024, 0, stream>>>(bsums, offs, nScanH, N);
    scanCH_kernel<<<nScanH, B, 0, stream>>>(gHist, bsums, scanned, TOT, NB);
    scatterC_kernel<<<TB, 512, 0, stream>>>(row, col, ew, scanned, semi, E, NB, chunkE);
    fineD_kernel<<<NB, 256, 0, stream>>>(semi, scanned, offs, dinv, perm, E, N, NB);
    normE_kernel<<<cdiv(N, B), B, 0, stream>>>(offs, dinv, perm, N);

    // --- conv1: agg = A*x (40-wide bf16), H1 = relu(agg@W1 + b1) -> bufH (bf16) ---
    gather_kernel<40><<<cdiv((long)N * 10, B), B, 0, stream>>>(
        offs, perm, xbf, dinv, bufA, N);
    gemm_kernel<40, 40, 320, false, true><<<cdiv(N, 128), 320, 0, stream>>>(
        bufA, W1, b1, bufH, nullptr, nullptr, N);

    // --- conv2: agg = A*H1 (40-wide bf16), H2 = relu(agg@W2 + b2) -> bufH (bf16) ---
    gather_kernel<40><<<cdiv((long)N * 10, B), B, 0, stream>>>(
        offs, perm, bufH, dinv, bufA, N);
    gemm_kernel<40, 80, 320, false, true><<<cdiv(N, 64), 320, 0, stream>>>(
        bufA, W2, b2, bufH, nullptr, nullptr, N);

    // --- conv3: agg = A*H2 (80-wide bf16), pool(relu(agg@W3 + b3)) -> g ---
    gather_kernel<80><<<cdiv((long)N * 20, B), B, 0, stream>>>(
        offs, perm, bufH, dinv, bufA, N);
    hipMemsetAsync(g, 0, (size_t)512 * 128 * 4, stream);
    gemm_kernel<80, 128, 256, true, false><<<cdiv(N, 32), 256, 0, stream>>>(
        bufA, W3, b3, nullptr, batch, (unsigned int*)g, N);

    // --- MLP + softmax ---
    fc_kernel<<<512, 256, 0, stream>>>(g, Wfc1, bfc1, Wfc2, bfc2, (float*)d_out);
}